// Round 9
// baseline (2526.412 us; speedup 1.0000x reference)
//
#include <hip/hip_runtime.h>
#include <stdint.h>
#include <stddef.h>

#define NTS 256

typedef short bf16x8 __attribute__((ext_vector_type(8)));
typedef short bf16x4 __attribute__((ext_vector_type(4)));
typedef float f32x4 __attribute__((ext_vector_type(4)));
typedef float f32x2 __attribute__((ext_vector_type(2)));

__device__ __forceinline__ unsigned short f2bf(float f) {
  union { float f; unsigned u; } c; c.f = f;
  unsigned u = c.u;
  u += 0x7fffu + ((u >> 16) & 1u);   // round-to-nearest-even (proven)
  return (unsigned short)(u >> 16);
}

// Fragment-ordered weight panels (unchanged):
// wpF[pan(18)][fb(32)][lane(64)][e(8)] bf16
//   pan 0..1 -> W1 K-blocks, pan 2..17 -> W2 K-blocks (pan-2)
//   value = W[k = pank*32 + (lane>>4)*8 + e][f = fb*16 + (lane&15)]
__global__ __launch_bounds__(256) void prep_weights(const float* __restrict__ W1,
                                                    const float* __restrict__ W2,
                                                    unsigned short* __restrict__ wp) {
  int gid = blockIdx.x * 256 + threadIdx.x;
  if (gid >= 294912) return;
  int e = gid & 7, lane = (gid >> 3) & 63, fb = (gid >> 9) & 31, pan = gid >> 14;
  int q = lane >> 4, j = lane & 15, f = fb * 16 + j;
  float v;
  if (pan < 2) v = W1[(pan * 32 + q * 8 + e) * 512 + f];
  else         v = W2[((pan - 2) * 32 + q * 8 + e) * 512 + f];
  wp[gid] = f2bf(v);
}

// DMA one panel's per-wave slice (2KB now: 16 waves) into LDS (W1 residency).
__device__ __forceinline__ void stage_panel16(const unsigned short* __restrict__ wp,
                                              int pan, char* dst_base, int wv, int lane) {
#pragma unroll
  for (int i = 0; i < 2; ++i) {
    const unsigned short* g = wp + (size_t)pan * 16384 + (wv * 2 + i) * 512 + lane * 8;
    char* l = dst_base + wv * 2048 + i * 1024;  // HW adds lane*16
    __builtin_amdgcn_global_load_lds((const __attribute__((address_space(1))) void*)g,
                                     (__attribute__((address_space(3))) void*)l,
                                     16, 0, 0);
  }
}

// LDS map (bytes), total 161792 <= 163840:
//   [0,      65536)  w1L  [pan(2)][fb(32)][lane(64)][16B]
//   [65536, 131072)  h1C  [ks(16)][nt(4)][lane(64)][16B]
//   [131072,139264)  histC [blk(8)][lane(64)][16B] (in-place shift, waves 0-7)
//   [139264,143360)  h0L u32[2][512] double-buffered elem-0 of each hist block
//   [143360,147456)  p0L f32[16][64]
//   [147456,151552)  p1L f32[16][64]
//   [151552,153600)  dwL f32[8][64]
//   [153600,155648)  b1L f32[512]
//   [155648,157696)  b2L f32[512]
//   [157696,161792)  w3L f32[512][2]
__global__ __launch_bounds__(1024) void po_fused(
    const float* __restrict__ dw, const float* __restrict__ x_init,
    const float* __restrict__ exp_arr, const float* __restrict__ b1,
    const float* __restrict__ b2, const float* __restrict__ W3,
    const float* __restrict__ b3, const unsigned short* __restrict__ wp,
    float* __restrict__ out) {
  extern __shared__ char smem[];
  char* const w1L = smem;
  char* const h1C = smem + 65536;
  char* const histC = smem + 131072;
  unsigned int* const h0L = (unsigned int*)(smem + 139264);
  float* const p0L = (float*)(smem + 143360);
  float* const p1L = (float*)(smem + 147456);
  float* const dwL = (float*)(smem + 151552);
  float* const b1L = (float*)(smem + 153600);
  float* const b2L = (float*)(smem + 155648);
  float* const w3L = (float*)(smem + 157696);

  const int tid = threadIdx.x;
  const int lane = tid & 63;
  const int wv = tid >> 6;          // 0..15
  const int q = lane >> 4;
  const int j = lane & 15;
  const int wg = blockIdx.x;

  // ---------------- init ----------------
  if (tid < 512) b1L[tid] = b1[tid];
  else           b2L[tid - 512] = b2[tid - 512];
  w3L[tid] = W3[tid];

  // hist block (waves 0-7 own histC): block index = wv, within-block (q,j)
  const int b_h = (wv & 3) * 16 + j;        // batch row of this hist block
  if (tid < 512) {
    const int k0 = (wv >> 2) * 32 + q * 8;
    const float* src = x_init + ((size_t)wg * 64 + b_h) * 64 + k0;
    bf16x8 v;
#pragma unroll
    for (int e = 0; e < 8; ++e) v[e] = (short)f2bf(src[e]);
    *(bf16x8*)(histC + tid * 16) = v;
    h0L[tid] = (unsigned int)(unsigned short)v[0];   // buffer 0 (read at t=0)
  }

  // replicated per-row dynamic state: row = lane (identical in all 16 waves)
  float xreg, yreg, rreg = 0.f;
  {
    const float* row = x_init + ((size_t)wg * 64 + lane) * 64;
    float y0 = 0.f;
    for (int k = 0; k < 63; ++k) y0 += exp_arr[k] * row[1 + k];
    yreg = y0 * 0.04f + (1.f - __expf(-2.52f)) * row[0];  // GEOMETRIC_SUM
    xreg = row[63];
  }
  const float b30 = b3[0], b31 = b3[1];

  // W1 -> LDS once (resident all 256 steps)
  stage_panel16(wp, 0, w1L, wv, lane);
  stage_panel16(wp, 1, w1L + 32768, wv, lane);

  // W2 direct-load geometry: each wave owns 2 fb slices (mt in 0..1)
  const unsigned short* const wpW2 = wp + 32768;
  const int wfo = wv * 1024 + lane * 8;     // + mt*512 (+ panel*16384)

  bf16x8 wA[2], wB[2];
#pragma unroll
  for (int mt = 0; mt < 2; ++mt)
    wA[mt] = *(const bf16x8*)(wpW2 + wfo + mt * 512);

  __syncthreads();   // drains W1 DMA + init LDS stores

  f32x4 acc[2][4];

#pragma unroll 1
  for (int t = 0; t < NTS; ++t) {
    // ---- dw tile staging every 8 steps ----
    if ((t & 7) == 0 && tid < 512) {
      int b = tid >> 3, c = tid & 7;
      dwL[c * 64 + b] = dw[((size_t)wg * 64 + b) * NTS + t + c];
    }

    // ---- Layer 1: W1 (LDS) @ histT ----
#pragma unroll
    for (int mt = 0; mt < 2; ++mt)
#pragma unroll
      for (int nt = 0; nt < 4; ++nt) acc[mt][nt] = (f32x4){0.f, 0.f, 0.f, 0.f};
#pragma unroll
    for (int p = 0; p < 2; ++p) {
      const char* pb = w1L + p * 32768 + wv * 2048;
      bf16x8 bfr[4];
#pragma unroll
      for (int nt = 0; nt < 4; ++nt)
        bfr[nt] = *(const bf16x8*)(histC + ((p * 4 + nt) * 64 + lane) * 16);
#pragma unroll
      for (int mt = 0; mt < 2; ++mt) {
        bf16x8 afr = *(const bf16x8*)(pb + mt * 1024 + lane * 16);
#pragma unroll
        for (int nt = 0; nt < 4; ++nt)
          acc[mt][nt] = __builtin_amdgcn_mfma_f32_16x16x32_bf16(afr, bfr[nt],
                                                                acc[mt][nt], 0, 0, 0);
      }
    }
    // h1 epilogue: relu(+b1) -> bf16 -> h1C (each wave writes its own ks=wv block)
#pragma unroll
    for (int mt = 0; mt < 2; ++mt) {
      int f0 = wv * 32 + mt * 16 + q * 4;
      f32x4 b1v = *(const f32x4*)(b1L + f0);
      int wb = ((f0 >> 5) * 256 + ((f0 >> 3) & 3) * 16 + j) * 16 + (f0 & 7) * 2;
#pragma unroll
      for (int nt = 0; nt < 4; ++nt) {
        bf16x4 pk;
#pragma unroll
        for (int r = 0; r < 4; ++r)
          pk[r] = (short)f2bf(fmaxf(acc[mt][nt][r] + b1v[r], 0.f));
        *(bf16x4*)(h1C + wb + nt * 1024) = pk;
      }
    }
    __syncthreads();  // (A) h1C + dwL visible

    // ---- Layer 2: 16 K-panels, weights L2->VGPR, 2-stage pipeline ----
#pragma unroll
    for (int mt = 0; mt < 2; ++mt)
#pragma unroll
      for (int nt = 0; nt < 4; ++nt) acc[mt][nt] = (f32x4){0.f, 0.f, 0.f, 0.f};
    {
      const unsigned short* pb = wpW2;
      const char* h1p = h1C;
#pragma unroll 1
      for (int kk = 0; kk < 8; ++kk) {
#pragma unroll
        for (int mt = 0; mt < 2; ++mt)
          wB[mt] = *(const bf16x8*)(pb + 16384 + wfo + mt * 512);
        __builtin_amdgcn_s_setprio(1);
#pragma unroll
        for (int nt = 0; nt < 4; ++nt) {
          bf16x8 bfr = *(const bf16x8*)(h1p + nt * 1024 + lane * 16);
#pragma unroll
          for (int mt = 0; mt < 2; ++mt)
            acc[mt][nt] = __builtin_amdgcn_mfma_f32_16x16x32_bf16(wA[mt], bfr,
                                                                  acc[mt][nt], 0, 0, 0);
        }
        __builtin_amdgcn_s_setprio(0);
        {
          const unsigned short* pn = (kk == 7) ? wpW2 : (pb + 32768);
#pragma unroll
          for (int mt = 0; mt < 2; ++mt)
            wA[mt] = *(const bf16x8*)(pn + wfo + mt * 512);
        }
        __builtin_amdgcn_s_setprio(1);
#pragma unroll
        for (int nt = 0; nt < 4; ++nt) {
          bf16x8 bfr = *(const bf16x8*)(h1p + 4096 + nt * 1024 + lane * 16);
#pragma unroll
          for (int mt = 0; mt < 2; ++mt)
            acc[mt][nt] = __builtin_amdgcn_mfma_f32_16x16x32_bf16(wB[mt], bfr,
                                                                  acc[mt][nt], 0, 0, 0);
        }
        __builtin_amdgcn_s_setprio(0);
        pb += 32768;
        h1p += 8192;
      }
    }

    // ---- Layer 3 folded: hoisted vector bias/W3 loads ----
    {
      float p0a[4] = {0.f, 0.f, 0.f, 0.f};
      float p1a[4] = {0.f, 0.f, 0.f, 0.f};
#pragma unroll
      for (int mt = 0; mt < 2; ++mt) {
        int f0 = wv * 32 + mt * 16 + q * 4;
        f32x4 b2v = *(const f32x4*)(b2L + f0);
        f32x4 w3a = *(const f32x4*)(w3L + f0 * 2);
        f32x4 w3b = *(const f32x4*)(w3L + f0 * 2 + 4);
#pragma unroll
        for (int nt = 0; nt < 4; ++nt) {
          float v0 = fmaxf(acc[mt][nt][0] + b2v[0], 0.f);
          float v1 = fmaxf(acc[mt][nt][1] + b2v[1], 0.f);
          float v2 = fmaxf(acc[mt][nt][2] + b2v[2], 0.f);
          float v3 = fmaxf(acc[mt][nt][3] + b2v[3], 0.f);
          p0a[nt] += v0 * w3a[0] + v1 * w3a[2] + v2 * w3b[0] + v3 * w3b[2];
          p1a[nt] += v0 * w3a[1] + v1 * w3a[3] + v2 * w3b[1] + v3 * w3b[3];
        }
      }
#pragma unroll
      for (int nt = 0; nt < 4; ++nt) {
        p0a[nt] += __shfl_xor(p0a[nt], 16);
        p0a[nt] += __shfl_xor(p0a[nt], 32);
        p1a[nt] += __shfl_xor(p1a[nt], 16);
        p1a[nt] += __shfl_xor(p1a[nt], 32);
        if (q == 0) {
          int b = nt * 16 + j;
          p0L[wv * 64 + b] = p0a[nt];
          p1L[wv * 64 + b] = p1a[nt];
        }
      }
    }
    __syncthreads();  // (B) p0L/p1L visible

    // ---- dynamics: replicated on ALL 16 waves (row = lane) ----
    float xn;
    {
      float z0 = b30, z1 = b31;
#pragma unroll
      for (int w = 0; w < 16; ++w) {
        z0 += p0L[w * 64 + lane];
        z1 += p1L[w * 64 + lane];
      }
      float pi0 = 2.f / (1.f + __expf(-z0));
      float pi1 = 2.f / (1.f + __expf(-z1));
      float x = xreg, y = yreg;
      float disc = __expf(-0.004f * (float)t);         // exp(-BETA*DT*t)
      float rv = fmaxf(pi0 * x, 0.f) + 1e-6f;
      rreg += (__logf(rv) * disc - fmaxf(-x, 0.f) * 100.f) * 0.04f;
      float dwv = dwL[(t & 7) * 64 + lane];
      float dxv = (0.06f * pi1 - pi0 + 0.02f) * x + 0.02f * y;
      xn = x + dxv * 0.04f + 0.2f * x * pi1 * dwv;
      yreg = y * 0.960789439152323f + xn * 0.04f;      // exp(-DT*LAMBD)
      xreg = xn;
    }

    // ---- hist shift (waves 0-7; all shuffles wave-uniform) ----
    if (tid < 512) {
      bf16x8 own = *(const bf16x8*)(histC + tid * 16);
      int e0 = (int)(unsigned short)own[0];
      int nbr = __shfl_down(e0, 16);          // next q, same (wv,j)
      float xb = __shfl(xn, b_h);             // full wave active -> defined
      unsigned short xbf = f2bf(xb);
      unsigned short last;
      if (q == 3) {
        last = (wv >= 4) ? xbf               // k0+8 == 64 -> append new x
                         : (unsigned short)h0L[(t & 1) * 512 + tid + 208];
      } else {
        last = (unsigned short)nbr;
      }
      bf16x8 nw;
#pragma unroll
      for (int e = 0; e < 7; ++e) nw[e] = own[e + 1];
      nw[7] = (short)last;
      *(bf16x8*)(histC + tid * 16) = nw;
      h0L[((t + 1) & 1) * 512 + tid] = (unsigned int)(unsigned short)nw[0];
    }
    __syncthreads();  // (C) histC + h0L stable for next step
  }

  if (tid < 64) {
    float rw = rreg + __logf(fmaxf(xreg + 0.5f * yreg, 0.f) + 1e-6f) * 10.f * __expf(-1.024f);
    rw -= fmaxf(-xreg, 0.f) * 100.f;
    out[(size_t)wg * 64 + tid] = -rw;
  }
}

extern "C" void kernel_launch(void* const* d_in, const int* in_sizes, int n_in,
                              void* d_out, int out_size, void* d_ws, size_t ws_size,
                              hipStream_t stream) {
  const float* dw      = (const float*)d_in[0];
  const float* x_init  = (const float*)d_in[1];
  const float* exp_arr = (const float*)d_in[2];
  const float* W1      = (const float*)d_in[3];
  const float* b1      = (const float*)d_in[4];
  const float* W2      = (const float*)d_in[5];
  const float* b2      = (const float*)d_in[6];
  const float* W3      = (const float*)d_in[7];
  const float* b3      = (const float*)d_in[8];
  unsigned short* wp = (unsigned short*)d_ws;  // needs 576KB
  float* out = (float*)d_out;

  (void)hipFuncSetAttribute((const void*)po_fused,
                            hipFuncAttributeMaxDynamicSharedMemorySize, 160 * 1024);

  prep_weights<<<1152, 256, 0, stream>>>(W1, W2, wp);
  po_fused<<<256, 1024, 161792, stream>>>(dw, x_init, exp_arr, b1, b2, W3, b3, wp, out);
}

// Round 10
// 2182.713 us; speedup vs baseline: 1.1575x; 1.1575x over previous
//
#include <hip/hip_runtime.h>
#include <stdint.h>
#include <stddef.h>

#define NTS 256

typedef short bf16x8 __attribute__((ext_vector_type(8)));
typedef short bf16x4 __attribute__((ext_vector_type(4)));
typedef float f32x4 __attribute__((ext_vector_type(4)));
typedef float f32x2 __attribute__((ext_vector_type(2)));
typedef unsigned int u32x2 __attribute__((ext_vector_type(2)));

__device__ __forceinline__ unsigned short f2bf(float f) {
  union { float f; unsigned u; } c; c.f = f;
  unsigned u = c.u;
  u += 0x7fffu + ((u >> 16) & 1u);   // round-to-nearest-even (proven)
  return (unsigned short)(u >> 16);
}

// pack two f32 -> two bf16 (RNE; r7 proved bit-compat with f2bf)
__device__ __forceinline__ unsigned cvt_pk_bf16(float lo, float hi) {
  unsigned r;
  asm("v_cvt_pk_bf16_f32 %0, %1, %2" : "=v"(r) : "v"(lo), "v"(hi));
  return r;
}

// Fragment-ordered weight panels (unchanged):
// wpF[pan(18)][fb(32)][lane(64)][e(8)] bf16
//   pan 0..1 -> W1 K-blocks, pan 2..17 -> W2 K-blocks (pan-2)
//   value = W[k = pank*32 + (lane>>4)*8 + e][f = fb*16 + (lane&15)]
__global__ __launch_bounds__(256) void prep_weights(const float* __restrict__ W1,
                                                    const float* __restrict__ W2,
                                                    unsigned short* __restrict__ wp) {
  int gid = blockIdx.x * 256 + threadIdx.x;
  if (gid >= 294912) return;
  int e = gid & 7, lane = (gid >> 3) & 63, fb = (gid >> 9) & 31, pan = gid >> 14;
  int q = lane >> 4, j = lane & 15, f = fb * 16 + j;
  float v;
  if (pan < 2) v = W1[(pan * 32 + q * 8 + e) * 512 + f];
  else         v = W2[((pan - 2) * 32 + q * 8 + e) * 512 + f];
  wp[gid] = f2bf(v);
}

// DMA one panel's per-wave slice (4KB) into LDS (used once, for W1 residency).
__device__ __forceinline__ void stage_panel(const unsigned short* __restrict__ wp,
                                            int pan, char* dst_base, int wv, int lane) {
#pragma unroll
  for (int i = 0; i < 4; ++i) {
    const unsigned short* g = wp + (size_t)pan * 16384 + (wv * 4 + i) * 512 + lane * 8;
    char* l = dst_base + wv * 4096 + i * 1024;  // HW adds lane*16
    __builtin_amdgcn_global_load_lds((const __attribute__((address_space(1))) void*)g,
                                     (__attribute__((address_space(3))) void*)l,
                                     16, 0, 0);
  }
}

// LDS map (bytes):
//   [0,      65536)  w1L: W1 resident [pan(2)][fb(32)][lane(64)][16B]
//   [65536, 131072)  h1C [ks(16)][nt(4)][lane(64)][16B]
//   [131072,139264)  histC [blk(8)][lane(64)][16B] (in-place shift)
//   [139264,143360)  h0L u32[2][512] double-buffered elem-0 of each hist block
//   [143360,145408)  p0L f32[8][64]
//   [145408,147456)  p1L f32[8][64]
//   [147456,151552)  dwL f32[16][64]
//   [151552,153600)  b1L f32[512]
//   [153600,155648)  b2L f32[512]
//   [155648,159744)  w3L f32[512][2]
__global__ __launch_bounds__(512, 2) void po_fused(
    const float* __restrict__ dw, const float* __restrict__ x_init,
    const float* __restrict__ exp_arr, const float* __restrict__ b1,
    const float* __restrict__ b2, const float* __restrict__ W3,
    const float* __restrict__ b3, const unsigned short* __restrict__ wp,
    float* __restrict__ out) {
  extern __shared__ char smem[];
  char* const w1L = smem;
  char* const h1C = smem + 65536;
  char* const histC = smem + 131072;
  unsigned int* const h0L = (unsigned int*)(smem + 139264);
  float* const p0L = (float*)(smem + 143360);
  float* const p1L = (float*)(smem + 145408);
  float* const dwL = (float*)(smem + 147456);
  float* const b1L = (float*)(smem + 151552);
  float* const b2L = (float*)(smem + 153600);
  float* const w3L = (float*)(smem + 155648);

  const int tid = threadIdx.x;
  const int lane = tid & 63;
  const int wv = tid >> 6;
  const int q = lane >> 4;
  const int j = lane & 15;
  const int wg = blockIdx.x;

  // ---------------- init ----------------
  b1L[tid] = b1[tid];
  b2L[tid] = b2[tid];
  w3L[tid] = W3[tid];
  w3L[tid + 512] = W3[tid + 512];

  // hist block owned by this thread: block index = wv, within-block (q,j)
  const int b_h = (wv & 3) * 16 + j;        // batch row of this hist block
  {
    const int k0 = (wv >> 2) * 32 + q * 8;
    const float* src = x_init + ((size_t)wg * 64 + b_h) * 64 + k0;
    bf16x8 v;
#pragma unroll
    for (int e = 0; e < 8; ++e) v[e] = (short)f2bf(src[e]);
    *(bf16x8*)(histC + tid * 16) = v;
    h0L[tid] = (unsigned int)(unsigned short)v[0];   // buffer 0 (read at t=0)
  }

  // replicated per-row dynamic state: row = lane (identical in all 8 waves)
  float xreg, yreg, rreg = 0.f;
  {
    const float* row = x_init + ((size_t)wg * 64 + lane) * 64;
    float y0 = 0.f;
    for (int k = 0; k < 63; ++k) y0 += exp_arr[k] * row[1 + k];
    yreg = y0 * 0.04f + (1.f - __expf(-2.52f)) * row[0];  // GEOMETRIC_SUM
    xreg = row[63];
  }
  const float b30 = b3[0], b31 = b3[1];

  // W1 -> LDS once (resident all 256 steps)
  stage_panel(wp, 0, w1L, wv, lane);
  stage_panel(wp, 1, w1L + 32768, wv, lane);

  // W2 direct-load geometry
  const unsigned short* const wpW2 = wp + 32768;
  const int wfo = wv * 2048 + lane * 8;     // + mt*512 (+ panel*16384)

  // 4-buffer, 2-deep W2 register pipeline: w0..w3 <- panels 0..3
  bf16x8 w0[4], w1r[4], w2r[4], w3r[4];
#pragma unroll
  for (int mt = 0; mt < 4; ++mt) {
    w0[mt]  = *(const bf16x8*)(wpW2 + 0 * 16384 + wfo + mt * 512);
    w1r[mt] = *(const bf16x8*)(wpW2 + 1 * 16384 + wfo + mt * 512);
    w2r[mt] = *(const bf16x8*)(wpW2 + 2 * 16384 + wfo + mt * 512);
    w3r[mt] = *(const bf16x8*)(wpW2 + 3 * 16384 + wfo + mt * 512);
  }

  __syncthreads();   // drains W1 DMA + init LDS stores

  f32x4 acc[4][4];

  // One W2 phase: 4 h1 B-frags, 16 MFMA with wreg, then reload wreg from wsrc
  // (reload-after-use; next use is 3 phases later => ~460cy latency tolerance)
  auto w2_phase = [&](bf16x8 (&wreg)[4], const char* h1b,
                      const unsigned short* wsrc) {
    bf16x8 bfr[4];
#pragma unroll
    for (int nt = 0; nt < 4; ++nt)
      bfr[nt] = *(const bf16x8*)(h1b + nt * 1024 + lane * 16);
    __builtin_amdgcn_s_setprio(1);
#pragma unroll
    for (int nt = 0; nt < 4; ++nt)
#pragma unroll
      for (int mt = 0; mt < 4; ++mt)
        acc[mt][nt] = __builtin_amdgcn_mfma_f32_16x16x32_bf16(wreg[mt], bfr[nt],
                                                              acc[mt][nt], 0, 0, 0);
    __builtin_amdgcn_s_setprio(0);
#pragma unroll
    for (int mt = 0; mt < 4; ++mt)
      wreg[mt] = *(const bf16x8*)(wsrc + wfo + mt * 512);
  };

#pragma unroll 1
  for (int t = 0; t < NTS; ++t) {
    // ---- dw tile staging every 16 steps ----
    if ((t & 15) == 0) {
      int b = tid >> 3, c = tid & 7;
      f32x2 v = *(const f32x2*)(dw + ((size_t)wg * 64 + b) * NTS + t + c * 2);
      dwL[(c * 2) * 64 + b] = v[0];
      dwL[(c * 2 + 1) * 64 + b] = v[1];
    }

    // ---- Layer 1: W1 (LDS) @ histT ----
#pragma unroll
    for (int mt = 0; mt < 4; ++mt)
#pragma unroll
      for (int nt = 0; nt < 4; ++nt) acc[mt][nt] = (f32x4){0.f, 0.f, 0.f, 0.f};
#pragma unroll
    for (int p = 0; p < 2; ++p) {
      const char* pb = w1L + p * 32768 + wv * 4096;
      bf16x8 bfr[4];
#pragma unroll
      for (int nt = 0; nt < 4; ++nt)
        bfr[nt] = *(const bf16x8*)(histC + ((p * 4 + nt) * 64 + lane) * 16);
#pragma unroll
      for (int mt = 0; mt < 4; ++mt) {
        bf16x8 afr = *(const bf16x8*)(pb + mt * 1024 + lane * 16);
#pragma unroll
        for (int nt = 0; nt < 4; ++nt)
          acc[mt][nt] = __builtin_amdgcn_mfma_f32_16x16x32_bf16(afr, bfr[nt],
                                                                acc[mt][nt], 0, 0, 0);
      }
    }
    // h1 epilogue: relu(+b1) -> bf16 via cvt_pk (RNE, bit-compat) -> h1C
#pragma unroll
    for (int mt = 0; mt < 4; ++mt) {
      int f0 = wv * 64 + mt * 16 + q * 4;
      f32x4 b1v = *(const f32x4*)(b1L + f0);
      int wb = ((f0 >> 5) * 256 + ((f0 >> 3) & 3) * 16 + j) * 16 + (f0 & 7) * 2;
#pragma unroll
      for (int nt = 0; nt < 4; ++nt) {
        float v0 = fmaxf(acc[mt][nt][0] + b1v[0], 0.f);
        float v1 = fmaxf(acc[mt][nt][1] + b1v[1], 0.f);
        float v2 = fmaxf(acc[mt][nt][2] + b1v[2], 0.f);
        float v3 = fmaxf(acc[mt][nt][3] + b1v[3], 0.f);
        u32x2 pk;
        pk[0] = cvt_pk_bf16(v0, v1);
        pk[1] = cvt_pk_bf16(v2, v3);
        *(u32x2*)(h1C + wb + nt * 1024) = pk;
      }
    }
    __syncthreads();  // (A) h1C + dwL visible

    // ---- Layer 2: 16 K-panels, 4-buffer 2-deep L2->VGPR pipeline ----
#pragma unroll
    for (int mt = 0; mt < 4; ++mt)
#pragma unroll
      for (int nt = 0; nt < 4; ++nt) acc[mt][nt] = (f32x4){0.f, 0.f, 0.f, 0.f};
    {
      const unsigned short* pb = wpW2;
      const char* h1p = h1C;
#pragma unroll 1
      for (int a = 0; a < 4; ++a) {
        // reload targets: panels 4a+4 .. 4a+7, wrapping to next step's 0..3
        const unsigned short* pn = (a == 3) ? wpW2 : (pb + 4 * 16384);
        w2_phase(w0,  h1p,         pn);
        w2_phase(w1r, h1p + 4096,  pn + 16384);
        w2_phase(w2r, h1p + 8192,  pn + 32768);
        w2_phase(w3r, h1p + 12288, pn + 49152);
        pb += 4 * 16384;
        h1p += 16384;
      }
    }

    // ---- Layer 3 folded: hoisted vector bias/W3 loads ----
    {
      float p0a[4] = {0.f, 0.f, 0.f, 0.f};
      float p1a[4] = {0.f, 0.f, 0.f, 0.f};
#pragma unroll
      for (int mt = 0; mt < 4; ++mt) {
        int f0 = wv * 64 + mt * 16 + q * 4;
        f32x4 b2v = *(const f32x4*)(b2L + f0);
        f32x4 w3a = *(const f32x4*)(w3L + f0 * 2);
        f32x4 w3b = *(const f32x4*)(w3L + f0 * 2 + 4);
#pragma unroll
        for (int nt = 0; nt < 4; ++nt) {
          float v0 = fmaxf(acc[mt][nt][0] + b2v[0], 0.f);
          float v1 = fmaxf(acc[mt][nt][1] + b2v[1], 0.f);
          float v2 = fmaxf(acc[mt][nt][2] + b2v[2], 0.f);
          float v3 = fmaxf(acc[mt][nt][3] + b2v[3], 0.f);
          p0a[nt] += v0 * w3a[0] + v1 * w3a[2] + v2 * w3b[0] + v3 * w3b[2];
          p1a[nt] += v0 * w3a[1] + v1 * w3a[3] + v2 * w3b[1] + v3 * w3b[3];
        }
      }
#pragma unroll
      for (int nt = 0; nt < 4; ++nt) {
        p0a[nt] += __shfl_xor(p0a[nt], 16);
        p0a[nt] += __shfl_xor(p0a[nt], 32);
        p1a[nt] += __shfl_xor(p1a[nt], 16);
        p1a[nt] += __shfl_xor(p1a[nt], 32);
        if (q == 0) {
          int b = nt * 16 + j;
          p0L[wv * 64 + b] = p0a[nt];
          p1L[wv * 64 + b] = p1a[nt];
        }
      }
    }
    __syncthreads();  // (B) p0L/p1L visible

    // ---- dynamics: replicated on ALL waves (row = lane) ----
    float xn;
    {
      float z0 = b30, z1 = b31;
#pragma unroll
      for (int w = 0; w < 8; ++w) {
        z0 += p0L[w * 64 + lane];
        z1 += p1L[w * 64 + lane];
      }
      float pi0 = 2.f / (1.f + __expf(-z0));
      float pi1 = 2.f / (1.f + __expf(-z1));
      float x = xreg, y = yreg;
      float disc = __expf(-0.004f * (float)t);         // exp(-BETA*DT*t)
      float rv = fmaxf(pi0 * x, 0.f) + 1e-6f;
      rreg += (__logf(rv) * disc - fmaxf(-x, 0.f) * 100.f) * 0.04f;
      float dwv = dwL[(t & 15) * 64 + lane];
      float dxv = (0.06f * pi1 - pi0 + 0.02f) * x + 0.02f * y;
      xn = x + dxv * 0.04f + 0.2f * x * pi1 * dwv;
      yreg = y * 0.960789439152323f + xn * 0.04f;      // exp(-DT*LAMBD)
      xreg = xn;
    }

    // ---- hist shift: ALL shuffles uniform (exec-mask-safe), then select ----
    {
      bf16x8 own = *(const bf16x8*)(histC + tid * 16);
      int e0 = (int)(unsigned short)own[0];
      int nbr = __shfl_down(e0, 16);          // uniform: all 64 lanes execute
      float xb = __shfl(xn, b_h);             // uniform: all 64 lanes execute
      unsigned short xbf = f2bf(xb);
      unsigned short last;
      if (q == 3) {
        last = (wv >= 4) ? xbf               // k0+8 == 64 -> append new x
                         : (unsigned short)h0L[(t & 1) * 512 + tid + 208];
      } else {
        last = (unsigned short)nbr;
      }
      bf16x8 nw;
#pragma unroll
      for (int e = 0; e < 7; ++e) nw[e] = own[e + 1];
      nw[7] = (short)last;
      *(bf16x8*)(histC + tid * 16) = nw;
      h0L[((t + 1) & 1) * 512 + tid] = (unsigned int)(unsigned short)nw[0];
    }
    __syncthreads();  // (C) histC + h0L stable for next step
  }

  if (tid < 64) {
    float rw = rreg + __logf(fmaxf(xreg + 0.5f * yreg, 0.f) + 1e-6f) * 10.f * __expf(-1.024f);
    rw -= fmaxf(-xreg, 0.f) * 100.f;
    out[(size_t)wg * 64 + tid] = -rw;
  }
}

extern "C" void kernel_launch(void* const* d_in, const int* in_sizes, int n_in,
                              void* d_out, int out_size, void* d_ws, size_t ws_size,
                              hipStream_t stream) {
  const float* dw      = (const float*)d_in[0];
  const float* x_init  = (const float*)d_in[1];
  const float* exp_arr = (const float*)d_in[2];
  const float* W1      = (const float*)d_in[3];
  const float* b1      = (const float*)d_in[4];
  const float* W2      = (const float*)d_in[5];
  const float* b2      = (const float*)d_in[6];
  const float* W3      = (const float*)d_in[7];
  const float* b3      = (const float*)d_in[8];
  unsigned short* wp = (unsigned short*)d_ws;  // needs 576KB
  float* out = (float*)d_out;

  (void)hipFuncSetAttribute((const void*)po_fused,
                            hipFuncAttributeMaxDynamicSharedMemorySize, 160 * 1024);

  prep_weights<<<1152, 256, 0, stream>>>(W1, W2, wp);
  po_fused<<<256, 512, 159744, stream>>>(dw, x_init, exp_arr, b1, b2, W3, b3, wp, out);
}